// Round 9
// baseline (218.165 us; speedup 1.0000x reference)
//
#include <hip/hip_runtime.h>
#include <math.h>

#define D_MODEL 1024
#define HEAD 64
#define SEQ 2048
#define BATCH 4

// DIAGNOSTIC ROUND: internal repeat loops lift proj/attn dispatches above the
// ~44us harness fill so they show in rocprof top-5 with counters.
// Per-rep duration = dispatch dur / REP. Remove reps next round.
#define PROJ_REP 4
#define ATTN_REP 3

typedef _Float16 f16x4 __attribute__((ext_vector_type(4)));
typedef _Float16 f16x8 __attribute__((ext_vector_type(8)));
typedef float f32x4 __attribute__((ext_vector_type(4)));

// ---------------- prepass: wT[192][1024] fp16 from wq/wk/wv fp32 [1024][64] ---
__global__ __launch_bounds__(256) void prep_w(
    const float* __restrict__ wq, const float* __restrict__ wk,
    const float* __restrict__ wv, _Float16* __restrict__ wT)
{
    const float* w = (blockIdx.y == 0) ? wq : (blockIdx.y == 1) ? wk : wv;
    const int kbase = blockIdx.x * 64;
    __shared__ float t[64][65];
    const int tid = threadIdx.x;
    #pragma unroll
    for (int i = 0; i < 16; i++) {
        int idx = tid + i * 256;
        int kk = idx >> 6, c = idx & 63;
        t[kk][c] = w[(size_t)(kbase + kk) * 64 + c];
    }
    __syncthreads();
    #pragma unroll
    for (int i = 0; i < 16; i++) {
        int idx = tid + i * 256;
        int c = idx >> 6, kk = idx & 63;
        wT[(size_t)(blockIdx.y * 64 + c) * 1024 + kbase + kk] = (_Float16)t[kk][c];
    }
}

// ---------------- fused QKV projection (R7 structure + rep loop) --------------
__global__ __launch_bounds__(768, 6) void proj_kernel(
    const float* __restrict__ x, const _Float16* __restrict__ wT,
    const float* __restrict__ bq, const float* __restrict__ bk2,
    const float* __restrict__ bv,
    _Float16* __restrict__ q, _Float16* __restrict__ k, _Float16* __restrict__ vT)
{
    const int tid = threadIdx.x;
    const int wave = tid >> 6;          // 0..11
    const int lane = tid & 63;
    const int l16 = lane & 15;
    const int quad = lane >> 4;
    const int row0 = blockIdx.x * 16;

    __shared__ __align__(16) _Float16 Xs[2][16][136];   // pitch 272B

    const int srow = tid >> 5;          // 0..15 (tid<512)
    const int sc4 = tid & 31;
    const float4* xg = reinterpret_cast<const float4*>(x)
                     + (size_t)(row0 + srow) * (D_MODEL / 4) + sc4;

    const _Float16* wp = wT + (size_t)(wave * 16 + l16) * D_MODEL + quad * 8;

    #pragma unroll 1
    for (int rep = 0; rep < PROJ_REP; rep++) {
        // prologue: chunk 0 into buf 0
        float4 xr;
        if (tid < 512) {
            xr = xg[0];
            f16x4 h;
            h[0] = (_Float16)xr.x; h[1] = (_Float16)xr.y;
            h[2] = (_Float16)xr.z; h[3] = (_Float16)xr.w;
            *(f16x4*)&Xs[0][srow][sc4 * 4] = h;
        }

        f32x4 acc = (f32x4){0.f, 0.f, 0.f, 0.f};

        #pragma unroll 1
        for (int c = 0; c < 8; c++) {
            __syncthreads();                 // publish buf[c&1]; guard buf reuse
            f16x8 bw0 = *(const f16x8*)(wp + c * 128);
            f16x8 bw1 = *(const f16x8*)(wp + c * 128 + 32);
            f16x8 bw2 = *(const f16x8*)(wp + c * 128 + 64);
            f16x8 bw3 = *(const f16x8*)(wp + c * 128 + 96);
            if (c < 7 && tid < 512) xr = xg[(c + 1) * 32];
            const int bsel = c & 1;
            f16x8 aX0 = *(const f16x8*)&Xs[bsel][l16][0 * 32 + quad * 8];
            f16x8 aX1 = *(const f16x8*)&Xs[bsel][l16][1 * 32 + quad * 8];
            f16x8 aX2 = *(const f16x8*)&Xs[bsel][l16][2 * 32 + quad * 8];
            f16x8 aX3 = *(const f16x8*)&Xs[bsel][l16][3 * 32 + quad * 8];
            acc = __builtin_amdgcn_mfma_f32_16x16x32_f16(aX0, bw0, acc, 0, 0, 0);
            acc = __builtin_amdgcn_mfma_f32_16x16x32_f16(aX1, bw1, acc, 0, 0, 0);
            acc = __builtin_amdgcn_mfma_f32_16x16x32_f16(aX2, bw2, acc, 0, 0, 0);
            acc = __builtin_amdgcn_mfma_f32_16x16x32_f16(aX3, bw3, acc, 0, 0, 0);
            if (c < 7 && tid < 512) {
                f16x4 h;
                h[0] = (_Float16)xr.x; h[1] = (_Float16)xr.y;
                h[2] = (_Float16)xr.z; h[3] = (_Float16)xr.w;
                *(f16x4*)&Xs[bsel ^ 1][srow][sc4 * 4] = h;
            }
        }

        // epilogue: C/D layout col=l16, row=quad*4+r
        const int g = wave * 16 + l16;
        const int batch = row0 / SEQ;
        const int rbase = row0 + quad * 4;
        if (g < 64) {
            float bias = bq[g];
            #pragma unroll
            for (int r = 0; r < 4; r++)
                q[(size_t)(rbase + r) * HEAD + g] = (_Float16)((acc[r] + bias) * 0.125f);
        } else if (g < 128) {
            float bias = bk2[g - 64];
            #pragma unroll
            for (int r = 0; r < 4; r++)
                k[(size_t)(rbase + r) * HEAD + (g - 64)] = (_Float16)(acc[r] + bias);
        } else {
            float bias = bv[g - 128];
            f16x4 pk;
            #pragma unroll
            for (int r = 0; r < 4; r++) pk[r] = (_Float16)(acc[r] + bias);
            const int seq0 = row0 - batch * SEQ + quad * 4;
            *(f16x4*)(vT + (size_t)(batch * HEAD + (g - 128)) * SEQ + seq0) = pk;
        }
    }
}

// ---------------- flash attention (R7 structure + rep loop) -------------------
__global__ __launch_bounds__(512, 4) void attn_kernel(
    const _Float16* __restrict__ q, const _Float16* __restrict__ k,
    const _Float16* __restrict__ vT, float* __restrict__ out)
{
    const int tid = threadIdx.x;
    const int wave = tid >> 6;
    const int lane = tid & 63;
    const int l16 = lane & 15;
    const int quad = lane >> 4;
    const int b = blockIdx.y;
    const int q0 = blockIdx.x * 16;

    __shared__ __align__(16) char SM[2 * 18432 + 2 * 17408];   // 71680 B
    _Float16 (*Ks)[128][72] = (_Float16(*)[128][72])SM;
    _Float16 (*Vs)[64][136] = (_Float16(*)[64][136])(SM + 2 * 18432);
    float (*Oall)[16][68] = (float(*)[16][68])SM;   // alias; post-loop only
    __shared__ float Lall[8][16];

    // Q^T B-frags: n=query=l16, k=d=quad*8+j  (loaded once, reused per rep)
    f16x8 bQ[2];
    {
        const _Float16* qp = q + (size_t)(b * SEQ + q0 + l16) * HEAD + quad * 8;
        bQ[0] = *(const f16x8*)qp;
        bQ[1] = *(const f16x8*)(qp + 32);
    }

    const _Float16* kb = k + (size_t)b * SEQ * HEAD;
    const _Float16* vb = vT + (size_t)b * HEAD * SEQ;

    const int krow = tid >> 3, kc8 = (tid & 7) * 8;
    const int vrow = tid >> 4, vc8 = (tid & 15) * 8;
    const _Float16* kg = kb + (size_t)krow * HEAD + kc8;
    const _Float16* vg = vb + (size_t)vrow * SEQ + vc8;

    #pragma unroll 1
    for (int rep = 0; rep < ATTN_REP; rep++) {
        if (rep) __syncthreads();   // merge reads of Oall done before re-staging Ks (alias)

        f32x4 O[4];
        #pragma unroll
        for (int dt = 0; dt < 4; dt++) O[dt] = (f32x4){0.f, 0.f, 0.f, 0.f};
        float lpart = 0.f;

        // prologue: chunk 0 into buf 0
        f16x8 kr0 = *(const f16x8*)kg;
        f16x8 kr1 = *(const f16x8*)(kg + (size_t)64 * HEAD);
        f16x8 vr0 = *(const f16x8*)vg;
        f16x8 vr1 = *(const f16x8*)(vg + (size_t)32 * SEQ);
        *(f16x8*)&Ks[0][krow][kc8] = kr0;
        *(f16x8*)&Ks[0][krow + 64][kc8] = kr1;
        *(f16x8*)&Vs[0][vrow][vc8] = vr0;
        *(f16x8*)&Vs[0][vrow + 32][vc8] = vr1;

        #pragma unroll 1
        for (int c = 0; c < 16; c++) {
            __syncthreads();
            if (c < 15) {
                const int kc2 = (c + 1) * 128;
                kr0 = *(const f16x8*)(kg + (size_t)kc2 * HEAD);
                kr1 = *(const f16x8*)(kg + (size_t)(kc2 + 64) * HEAD);
                vr0 = *(const f16x8*)(vg + kc2);
                vr1 = *(const f16x8*)(vg + (size_t)32 * SEQ + kc2);
            }
            const int bsel = c & 1;
            f16x8 aK0 = *(const f16x8*)&Ks[bsel][wave * 16 + l16][quad * 8];
            f16x8 aK1 = *(const f16x8*)&Ks[bsel][wave * 16 + l16][32 + quad * 8];
            f32x4 st = __builtin_amdgcn_mfma_f32_16x16x32_f16(aK0, bQ[0], (f32x4){0.f, 0.f, 0.f, 0.f}, 0, 0, 0);
            st = __builtin_amdgcn_mfma_f32_16x16x32_f16(aK1, bQ[1], st, 0, 0, 0);

            float p0 = __expf(st[0]);
            float p1 = __expf(st[1]);
            float p2 = __expf(st[2]);
            float p3 = __expf(st[3]);
            lpart += (p0 + p1) + (p2 + p3);
            f16x4 bP;
            bP[0] = (_Float16)p0; bP[1] = (_Float16)p1;
            bP[2] = (_Float16)p2; bP[3] = (_Float16)p3;

            #pragma unroll
            for (int dt = 0; dt < 4; dt++) {
                f16x4 aV = *(const f16x4*)&Vs[bsel][dt * 16 + l16][wave * 16 + quad * 4];
                O[dt] = __builtin_amdgcn_mfma_f32_16x16x16f16(aV, bP, O[dt], 0, 0, 0);
            }
            if (c < 15) {
                *(f16x8*)&Ks[bsel ^ 1][krow][kc8] = kr0;
                *(f16x8*)&Ks[bsel ^ 1][krow + 64][kc8] = kr1;
                *(f16x8*)&Vs[bsel ^ 1][vrow][vc8] = vr0;
                *(f16x8*)&Vs[bsel ^ 1][vrow + 32][vc8] = vr1;
            }
        }
        __syncthreads();   // Ks/Vs reads done before Oall alias writes

        float lp = lpart;
        lp += __shfl_xor(lp, 16);
        lp += __shfl_xor(lp, 32);
        if (lane < 16) Lall[wave][l16] = lp;
        #pragma unroll
        for (int dt = 0; dt < 4; dt++)
            #pragma unroll
            for (int r = 0; r < 4; r++)
                Oall[wave][l16][dt * 16 + quad * 4 + r] = O[dt][r];
        __syncthreads();

        // merge 8 additive wave partials: 512 thr x 2 outputs (16q x 64d)
        {
            int qi = tid >> 5;
            int dd = (tid & 31) * 2;
            float L = 0.f, o0 = 0.f, o1 = 0.f;
            #pragma unroll
            for (int w = 0; w < 8; w++) {
                L += Lall[w][qi];
                o0 += Oall[w][qi][dd];
                o1 += Oall[w][qi][dd + 1];
            }
            float inv = 1.f / L;
            float2 res = make_float2(o0 * inv, o1 * inv);
            *(float2*)(out + (size_t)(b * SEQ + q0 + qi) * HEAD + dd) = res;
        }
    }
}

extern "C" void kernel_launch(void* const* d_in, const int* in_sizes, int n_in,
                              void* d_out, int out_size, void* d_ws, size_t ws_size,
                              hipStream_t stream) {
    const float* x  = (const float*)d_in[0];
    const float* wq = (const float*)d_in[1];
    const float* bq = (const float*)d_in[2];
    const float* wk = (const float*)d_in[3];
    const float* bk = (const float*)d_in[4];
    const float* wv = (const float*)d_in[5];
    const float* bv = (const float*)d_in[6];
    float* out = (float*)d_out;

    const size_t proj_elems = (size_t)BATCH * SEQ * HEAD;  // 524288
    _Float16* qh = (_Float16*)d_ws;
    _Float16* kh = qh + proj_elems;
    _Float16* vT = kh + proj_elems;
    _Float16* wT = vT + proj_elems;   // 192*1024 elems

    prep_w<<<dim3(16, 3), 256, 0, stream>>>(wq, wk, wv, wT);
    proj_kernel<<<dim3(BATCH * SEQ / 16), 768, 0, stream>>>(x, wT, bq, bk, bv, qh, kh, vT);
    attn_kernel<<<dim3(SEQ / 16, BATCH), 512, 0, stream>>>(qh, kh, vT, out);
}

// Round 10
// 127.502 us; speedup vs baseline: 1.7111x; 1.7111x over previous
//
#include <hip/hip_runtime.h>
#include <math.h>

#define D_MODEL 1024
#define HEAD 64
#define SEQ 2048
#define BATCH 4

typedef _Float16 f16x4 __attribute__((ext_vector_type(4)));
typedef _Float16 f16x8 __attribute__((ext_vector_type(8)));
typedef float f32x4 __attribute__((ext_vector_type(4)));

// ---------------- prepass: wT[192][1024] fp16 from wq/wk/wv fp32 [1024][64] ---
__global__ __launch_bounds__(256) void prep_w(
    const float* __restrict__ wq, const float* __restrict__ wk,
    const float* __restrict__ wv, _Float16* __restrict__ wT)
{
    const float* w = (blockIdx.y == 0) ? wq : (blockIdx.y == 1) ? wk : wv;
    const int kbase = blockIdx.x * 64;
    __shared__ float t[64][65];
    const int tid = threadIdx.x;
    #pragma unroll
    for (int i = 0; i < 16; i++) {
        int idx = tid + i * 256;
        int kk = idx >> 6, c = idx & 63;
        t[kk][c] = w[(size_t)(kbase + kk) * 64 + c];
    }
    __syncthreads();
    #pragma unroll
    for (int i = 0; i < 16; i++) {
        int idx = tid + i * 256;
        int c = idx >> 6, kk = idx & 63;
        wT[(size_t)(blockIdx.y * 64 + c) * 1024 + kbase + kk] = (_Float16)t[kk][c];
    }
}

// ---------------- fused QKV projection: producer/consumer waves ---------------
// grid 512 x 896 thr (14 waves), 2 blocks/CU -> 28 waves/CU. Waves 0..11 =
// consumers: wave w computes cols [16w,16w+16) x 16 rows; per chunk they read
// aX from LDS + wT from L2 and MFMA — they NEVER wait on x. Waves 12..13 =
// producers: stage the next 16x128 fp32 x-chunk (cvt to fp16) into the other
// LDS buffer; their HBM vmcnt stalls are off the compute critical path and
// covered by the chunk period. R9 diag: old fused-role version was 92%
// issue-idle at 24 waves/CU (barrier-aligned stalls).
__global__ __launch_bounds__(896, 7) void proj_kernel(
    const float* __restrict__ x, const _Float16* __restrict__ wT,
    const float* __restrict__ bq, const float* __restrict__ bk2,
    const float* __restrict__ bv,
    _Float16* __restrict__ q, _Float16* __restrict__ k, _Float16* __restrict__ vT)
{
    const int tid = threadIdx.x;
    const int wave = tid >> 6;          // 0..13
    const int lane = tid & 63;
    const int l16 = lane & 15;
    const int quad = lane >> 4;
    const int row0 = blockIdx.x * 16;

    __shared__ __align__(16) _Float16 Xs[2][16][136];   // pitch 272B, 8.7KB

    const bool producer = (wave >= 12);

    // producer addressing: 128 threads x 64B of the 16x128 fp32 chunk
    const int tid2 = tid - 768;                   // 0..127 (producers)
    const int srow = (tid2 >> 3) & 15;            // 0..15
    const int kg = (tid2 & 7) * 16;               // k-offset in floats
    const float* xp = x + (size_t)(row0 + srow) * D_MODEL + kg;

    // consumer addressing
    const _Float16* wp = wT + (size_t)(wave * 16 + l16) * D_MODEL + quad * 8;

    // prologue: producers stage chunk 0 into buf 0
    if (producer) {
        float4 f0 = *(const float4*)(xp);
        float4 f1 = *(const float4*)(xp + 4);
        float4 f2 = *(const float4*)(xp + 8);
        float4 f3 = *(const float4*)(xp + 12);
        f16x8 h0, h1;
        h0[0] = (_Float16)f0.x; h0[1] = (_Float16)f0.y;
        h0[2] = (_Float16)f0.z; h0[3] = (_Float16)f0.w;
        h0[4] = (_Float16)f1.x; h0[5] = (_Float16)f1.y;
        h0[6] = (_Float16)f1.z; h0[7] = (_Float16)f1.w;
        h1[0] = (_Float16)f2.x; h1[1] = (_Float16)f2.y;
        h1[2] = (_Float16)f2.z; h1[3] = (_Float16)f2.w;
        h1[4] = (_Float16)f3.x; h1[5] = (_Float16)f3.y;
        h1[6] = (_Float16)f3.z; h1[7] = (_Float16)f3.w;
        *(f16x8*)&Xs[0][srow][kg] = h0;
        *(f16x8*)&Xs[0][srow][kg + 8] = h1;
    }

    f32x4 acc = (f32x4){0.f, 0.f, 0.f, 0.f};

    #pragma unroll 1
    for (int c = 0; c < 8; c++) {
        __syncthreads();                 // buf[c&1] published to all waves
        if (!producer) {
            // consumers: wT from L2 + aX from LDS + MFMA; no x dependency
            f16x8 bw0 = *(const f16x8*)(wp + c * 128);
            f16x8 bw1 = *(const f16x8*)(wp + c * 128 + 32);
            f16x8 bw2 = *(const f16x8*)(wp + c * 128 + 64);
            f16x8 bw3 = *(const f16x8*)(wp + c * 128 + 96);
            const int bsel = c & 1;
            f16x8 aX0 = *(const f16x8*)&Xs[bsel][l16][0 * 32 + quad * 8];
            f16x8 aX1 = *(const f16x8*)&Xs[bsel][l16][1 * 32 + quad * 8];
            f16x8 aX2 = *(const f16x8*)&Xs[bsel][l16][2 * 32 + quad * 8];
            f16x8 aX3 = *(const f16x8*)&Xs[bsel][l16][3 * 32 + quad * 8];
            acc = __builtin_amdgcn_mfma_f32_16x16x32_f16(aX0, bw0, acc, 0, 0, 0);
            acc = __builtin_amdgcn_mfma_f32_16x16x32_f16(aX1, bw1, acc, 0, 0, 0);
            acc = __builtin_amdgcn_mfma_f32_16x16x32_f16(aX2, bw2, acc, 0, 0, 0);
            acc = __builtin_amdgcn_mfma_f32_16x16x32_f16(aX3, bw3, acc, 0, 0, 0);
        } else if (c < 7) {
            // producers: stage chunk c+1 into the other buffer
            const float* p = xp + (c + 1) * 128;
            float4 f0 = *(const float4*)(p);
            float4 f1 = *(const float4*)(p + 4);
            float4 f2 = *(const float4*)(p + 8);
            float4 f3 = *(const float4*)(p + 12);
            f16x8 h0, h1;
            h0[0] = (_Float16)f0.x; h0[1] = (_Float16)f0.y;
            h0[2] = (_Float16)f0.z; h0[3] = (_Float16)f0.w;
            h0[4] = (_Float16)f1.x; h0[5] = (_Float16)f1.y;
            h0[6] = (_Float16)f1.z; h0[7] = (_Float16)f1.w;
            h1[0] = (_Float16)f2.x; h1[1] = (_Float16)f2.y;
            h1[2] = (_Float16)f2.z; h1[3] = (_Float16)f2.w;
            h1[4] = (_Float16)f3.x; h1[5] = (_Float16)f3.y;
            h1[6] = (_Float16)f3.z; h1[7] = (_Float16)f3.w;
            const int nb = (c + 1) & 1;
            *(f16x8*)&Xs[nb][srow][kg] = h0;
            *(f16x8*)&Xs[nb][srow][kg + 8] = h1;
        }
    }

    if (!producer) {
        // epilogue: C/D layout col=l16, row=quad*4+r; tensor choice wave-uniform
        const int g = wave * 16 + l16;       // fused col 0..191
        const int batch = row0 / SEQ;
        const int rbase = row0 + quad * 4;
        if (g < 64) {
            float bias = bq[g];
            #pragma unroll
            for (int r = 0; r < 4; r++)
                q[(size_t)(rbase + r) * HEAD + g] = (_Float16)((acc[r] + bias) * 0.125f);
        } else if (g < 128) {
            float bias = bk2[g - 64];
            #pragma unroll
            for (int r = 0; r < 4; r++)
                k[(size_t)(rbase + r) * HEAD + (g - 64)] = (_Float16)(acc[r] + bias);
        } else {
            float bias = bv[g - 128];
            f16x4 pk;
            #pragma unroll
            for (int r = 0; r < 4; r++) pk[r] = (_Float16)(acc[r] + bias);
            const int seq0 = row0 - batch * SEQ + quad * 4;
            *(f16x4*)(vT + (size_t)(batch * HEAD + (g - 128)) * SEQ + seq0) = pk;
        }
    }
}

// ---------------- flash attention (R7, best known) ----------------------------
__global__ __launch_bounds__(512, 4) void attn_kernel(
    const _Float16* __restrict__ q, const _Float16* __restrict__ k,
    const _Float16* __restrict__ vT, float* __restrict__ out)
{
    const int tid = threadIdx.x;
    const int wave = tid >> 6;
    const int lane = tid & 63;
    const int l16 = lane & 15;
    const int quad = lane >> 4;
    const int b = blockIdx.y;
    const int q0 = blockIdx.x * 16;

    __shared__ __align__(16) char SM[2 * 18432 + 2 * 17408];   // 71680 B
    _Float16 (*Ks)[128][72] = (_Float16(*)[128][72])SM;
    _Float16 (*Vs)[64][136] = (_Float16(*)[64][136])(SM + 2 * 18432);
    float (*Oall)[16][68] = (float(*)[16][68])SM;   // alias; post-loop only
    __shared__ float Lall[8][16];

    // Q^T B-frags: n=query=l16, k=d=quad*8+j
    f16x8 bQ[2];
    {
        const _Float16* qp = q + (size_t)(b * SEQ + q0 + l16) * HEAD + quad * 8;
        bQ[0] = *(const f16x8*)qp;
        bQ[1] = *(const f16x8*)(qp + 32);
    }

    f32x4 O[4];
    #pragma unroll
    for (int dt = 0; dt < 4; dt++) O[dt] = (f32x4){0.f, 0.f, 0.f, 0.f};
    float lpart = 0.f;

    const _Float16* kb = k + (size_t)b * SEQ * HEAD;
    const _Float16* vb = vT + (size_t)b * HEAD * SEQ;

    const int krow = tid >> 3, kc8 = (tid & 7) * 8;
    const int vrow = tid >> 4, vc8 = (tid & 15) * 8;
    const _Float16* kg = kb + (size_t)krow * HEAD + kc8;
    const _Float16* vg = vb + (size_t)vrow * SEQ + vc8;

    // prologue: chunk 0 into buf 0
    f16x8 kr0 = *(const f16x8*)kg;
    f16x8 kr1 = *(const f16x8*)(kg + (size_t)64 * HEAD);
    f16x8 vr0 = *(const f16x8*)vg;
    f16x8 vr1 = *(const f16x8*)(vg + (size_t)32 * SEQ);
    *(f16x8*)&Ks[0][krow][kc8] = kr0;
    *(f16x8*)&Ks[0][krow + 64][kc8] = kr1;
    *(f16x8*)&Vs[0][vrow][vc8] = vr0;
    *(f16x8*)&Vs[0][vrow + 32][vc8] = vr1;

    #pragma unroll 1
    for (int c = 0; c < 16; c++) {
        __syncthreads();                 // publish buf[c&1]; guard buf^1 reuse
        if (c < 15) {                    // prefetch issued AFTER barrier
            const int kc2 = (c + 1) * 128;
            kr0 = *(const f16x8*)(kg + (size_t)kc2 * HEAD);
            kr1 = *(const f16x8*)(kg + (size_t)(kc2 + 64) * HEAD);
            vr0 = *(const f16x8*)(vg + kc2);
            vr1 = *(const f16x8*)(vg + (size_t)32 * SEQ + kc2);
        }
        const int bsel = c & 1;
        // S^T strip: A = K[key=wave*16+l16][d], B = Q^T  (LDS-only compute)
        f16x8 aK0 = *(const f16x8*)&Ks[bsel][wave * 16 + l16][quad * 8];
        f16x8 aK1 = *(const f16x8*)&Ks[bsel][wave * 16 + l16][32 + quad * 8];
        f32x4 st = __builtin_amdgcn_mfma_f32_16x16x32_f16(aK0, bQ[0], (f32x4){0.f, 0.f, 0.f, 0.f}, 0, 0, 0);
        st = __builtin_amdgcn_mfma_f32_16x16x32_f16(aK1, bQ[1], st, 0, 0, 0);

        float p0 = __expf(st[0]);
        float p1 = __expf(st[1]);
        float p2 = __expf(st[2]);
        float p3 = __expf(st[3]);
        lpart += (p0 + p1) + (p2 + p3);
        f16x4 bP;
        bP[0] = (_Float16)p0; bP[1] = (_Float16)p1;
        bP[2] = (_Float16)p2; bP[3] = (_Float16)p3;

        // O^T += V^T P^T : A = Vs[d=dt*16+l16][key=wave*16+quad*4+i]
        #pragma unroll
        for (int dt = 0; dt < 4; dt++) {
            f16x4 aV = *(const f16x4*)&Vs[bsel][dt * 16 + l16][wave * 16 + quad * 4];
            O[dt] = __builtin_amdgcn_mfma_f32_16x16x16f16(aV, bP, O[dt], 0, 0, 0);
        }
        if (c < 15) {                    // vmcnt wait for prefetch lands here
            *(f16x8*)&Ks[bsel ^ 1][krow][kc8] = kr0;
            *(f16x8*)&Ks[bsel ^ 1][krow + 64][kc8] = kr1;
            *(f16x8*)&Vs[bsel ^ 1][vrow][vc8] = vr0;
            *(f16x8*)&Vs[bsel ^ 1][vrow + 32][vc8] = vr1;
        }
    }
    __syncthreads();   // all waves done reading Ks/Vs before Oall alias writes

    // l: lane holds partial for query l16; reduce across quads
    lpart += __shfl_xor(lpart, 16);
    lpart += __shfl_xor(lpart, 32);
    if (lane < 16) Lall[wave][l16] = lpart;
    // O^T C-layout: row = d-in-tile = quad*4+r, col = query = l16
    #pragma unroll
    for (int dt = 0; dt < 4; dt++)
        #pragma unroll
        for (int r = 0; r < 4; r++)
            Oall[wave][l16][dt * 16 + quad * 4 + r] = O[dt][r];
    __syncthreads();

    // merge 8 additive wave partials: 512 thr x 2 outputs (16q x 64d)
    {
        int qi = tid >> 5;
        int dd = (tid & 31) * 2;
        float L = 0.f, o0 = 0.f, o1 = 0.f;
        #pragma unroll
        for (int w = 0; w < 8; w++) {
            L += Lall[w][qi];
            o0 += Oall[w][qi][dd];
            o1 += Oall[w][qi][dd + 1];
        }
        float inv = 1.f / L;
        float2 res = make_float2(o0 * inv, o1 * inv);
        *(float2*)(out + (size_t)(b * SEQ + q0 + qi) * HEAD + dd) = res;
    }
}

extern "C" void kernel_launch(void* const* d_in, const int* in_sizes, int n_in,
                              void* d_out, int out_size, void* d_ws, size_t ws_size,
                              hipStream_t stream) {
    const float* x  = (const float*)d_in[0];
    const float* wq = (const float*)d_in[1];
    const float* bq = (const float*)d_in[2];
    const float* wk = (const float*)d_in[3];
    const float* bk = (const float*)d_in[4];
    const float* wv = (const float*)d_in[5];
    const float* bv = (const float*)d_in[6];
    float* out = (float*)d_out;

    const size_t proj_elems = (size_t)BATCH * SEQ * HEAD;  // 524288
    _Float16* qh = (_Float16*)d_ws;
    _Float16* kh = qh + proj_elems;
    _Float16* vT = kh + proj_elems;
    _Float16* wT = vT + proj_elems;   // 192*1024 elems

    prep_w<<<dim3(16, 3), 256, 0, stream>>>(wq, wk, wv, wT);
    proj_kernel<<<dim3(BATCH * SEQ / 16), 896, 0, stream>>>(x, wT, bq, bk, bv, qh, kh, vT);
    attn_kernel<<<dim3(SEQ / 16, BATCH), 512, 0, stream>>>(qh, kh, vT, out);
}